// Round 4
// baseline (1744.272 us; speedup 1.0000x reference)
//
#include <hip/hip_runtime.h>
#include <hip/hip_bf16.h>
#include <math.h>

// GAT x3 on N=100000 nodes, E=1600000 edges (+ self loops).
// Round 4: feature12 restructured — 4 threads per row (22 cols each), B staged
// in LDS (float2 reads, 16-lane broadcast). 6250 waves (24/CU) vs 1564 before.

#define NN 100000
#define NE 1600000
#define NT (NE + NN)
#define FIN 50
#define HID 40
#define COUT 121

typedef __attribute__((ext_vector_type(8))) short bf16x8;
typedef __attribute__((ext_vector_type(4))) float f32x4;

__device__ __forceinline__ float lrelu(float x) { return fmaxf(x, 0.2f * x); }
__device__ __forceinline__ float elu1(float x)  { return x > 0.f ? x : __expf(x) - 1.f; }

// ---------------- CSR build ----------------
__global__ __launch_bounds__(256)
void deg_init_kernel(int* __restrict__ deg) {
    int i = blockIdx.x * 256 + threadIdx.x;
    if (i < NN) deg[i] = 1;  // self loop
}

__global__ __launch_bounds__(256)
void hist_kernel(const int* __restrict__ edst, int* __restrict__ deg) {
    int e = blockIdx.x * 256 + threadIdx.x;
    if (e < NE) atomicAdd(&deg[edst[e]], 1);
}

__global__ __launch_bounds__(256)
void scan_block_kernel(const int* __restrict__ deg, int* __restrict__ off,
                       int* __restrict__ bsum) {
    __shared__ int s[256];
    int t = threadIdx.x, b = blockIdx.x, i = b * 256 + t;
    int v = (i < NN) ? deg[i] : 0;
    s[t] = v; __syncthreads();
#pragma unroll
    for (int o = 1; o < 256; o <<= 1) {
        int x = (t >= o) ? s[t - o] : 0;
        __syncthreads();
        s[t] += x;
        __syncthreads();
    }
    if (i < NN) off[i] = s[t] - v;
    if (t == 255) bsum[b] = s[255];
}

__global__ __launch_bounds__(256)
void scan_bsum_kernel(const int* __restrict__ bsum, int* __restrict__ bscan, int nb) {
    __shared__ int s[256];
    int t = threadIdx.x;
    int carry = 0;
    int nc = (nb + 255) / 256;
    for (int c = 0; c < nc; c++) {
        int i = c * 256 + t;
        int v = (i < nb) ? bsum[i] : 0;
        s[t] = v; __syncthreads();
#pragma unroll
        for (int o = 1; o < 256; o <<= 1) {
            int x = (t >= o) ? s[t - o] : 0;
            __syncthreads();
            s[t] += x;
            __syncthreads();
        }
        if (i < nb) bscan[i] = carry + s[t] - v;
        carry += s[255];
        __syncthreads();
    }
}

__global__ __launch_bounds__(256)
void place_kernel(int* __restrict__ off, const int* __restrict__ bscan,
                  int* __restrict__ sorted_src, int* __restrict__ cursor) {
    int i = blockIdx.x * 256 + threadIdx.x;
    if (i == 0) off[NN] = NT;
    if (i < NN) {
        int o = off[i] + bscan[i >> 8];
        off[i] = o;
        sorted_src[o] = i;   // self loop first
        cursor[i] = o + 1;
    }
}

__global__ __launch_bounds__(256)
void scatter_kernel(const int* __restrict__ esrc, const int* __restrict__ edst,
                    int* __restrict__ cursor, int* __restrict__ sorted_src) {
    int e = blockIdx.x * 256 + threadIdx.x;
    if (e < NE) {
        int d = edst[e];
        int p = atomicAdd(&cursor[d], 1);
        sorted_src[p] = esrc[e];
    }
}

// ---------------- fold weight blocks ----------------
__global__ __launch_bounds__(256)
void fold_B12_kernel(const float* __restrict__ W, const float* __restrict__ lw,
                     const float* __restrict__ as_, const float* __restrict__ ad_,
                     float* __restrict__ B, int F) {
    int t = blockIdx.x * 256 + threadIdx.x;
    if (t >= F * 88) return;
    int f = t / 88, j = t - f * 88;
    float v = 0.f;
    if (j < 40) v = W[f * 40 + j];
    else if (j < 80) v = lw[f * 40 + (j - 40)];
    else if (j < 84) {
        int h = j - 80; float s = 0.f;
        for (int d = 0; d < 10; d++) s += W[f * 40 + h * 10 + d] * as_[h * 10 + d];
        v = s;
    } else {
        int h = j - 84; float s = 0.f;
        for (int d = 0; d < 10; d++) s += W[f * 40 + h * 10 + d] * ad_[h * 10 + d];
        v = s;
    }
    B[t] = v;
}

__global__ __launch_bounds__(256)
void fold_B3_kernel(const float* __restrict__ W3, const float* __restrict__ as3,
                    const float* __restrict__ ad3, float* __restrict__ B) {
    int t = blockIdx.x * 256 + threadIdx.x;
    if (t >= 40 * 12) return;
    int f = t / 12, k = t - f * 12;
    float s = 0.f;
    if (k < 6) {
        int h = k;
        for (int c = 0; c < COUT; c++) s += W3[f * 726 + h * COUT + c] * as3[h * COUT + c];
    } else {
        int h = k - 6;
        for (int c = 0; c < COUT; c++) s += W3[f * 726 + h * COUT + c] * ad3[h * COUT + c];
    }
    B[t] = s;
}

// Fold W3/lw3 into bf16 MFMA B-fragment order (see round-3 comment).
__global__ __launch_bounds__(256)
void fold_Bf_kernel(const float* __restrict__ W3, const float* __restrict__ lw3,
                    __hip_bfloat16* __restrict__ Bf) {
    int t = blockIdx.x * 256 + threadIdx.x;
    if (t >= 9 * 8 * 64 * 8) return;
    int j = t & 7, lane = (t >> 3) & 63, ct = (t >> 9) & 7, kt = t >> 12;
    int k = kt * 32 + (lane >> 4) * 8 + j;
    int c = ct * 16 + (lane & 15);
    float v = 0.f;
    if (c < COUT) {
        if (k < 240) {
            int h = k / 40, f = k - h * 40;
            v = W3[f * 726 + h * COUT + c];
        } else if (k < 280) {
            int f = k - 240;
            v = lw3[f * COUT + c];
        }
    }
    Bf[t] = __float2bfloat16(v);
}

// ---------------- fused feature GEMM for layers 1/2 ----------------
// 4 threads per row, 22 cols each; B staged in LDS; 64 rows per 256-thr block.
template <int F>
__global__ __launch_bounds__(256)
void feature12_kernel(const float* A, const float* __restrict__ B,
                      const float* __restrict__ bias, const float* __restrict__ lbias,
                      float* __restrict__ xw, float* agg,
                      float* __restrict__ asrc, float* __restrict__ adst) {
    __shared__ float Bs[F * 88];
    for (int i = threadIdx.x; i < F * 88; i += 256) Bs[i] = B[i];
    __syncthreads();

    int g = blockIdx.x * 256 + threadIdx.x;
    int r = g >> 2, p = g & 3;
    if (r >= NN) return;

    float a[F];
    if (F % 4 == 0) {
        const float4* A4 = reinterpret_cast<const float4*>(A + (size_t)r * F);
#pragma unroll
        for (int q = 0; q < F / 4; q++) {
            float4 v = A4[q];
            a[4 * q] = v.x; a[4 * q + 1] = v.y; a[4 * q + 2] = v.z; a[4 * q + 3] = v.w;
        }
    } else {
        const float2* A2 = reinterpret_cast<const float2*>(A + (size_t)r * F);
#pragma unroll
        for (int q = 0; q < F / 2; q++) {
            float2 v = A2[q];
            a[2 * q] = v.x; a[2 * q + 1] = v.y;
        }
        if (F & 1) a[F - 1] = A[(size_t)r * F + F - 1];
    }

    const int j0 = p * 22;
    float2 acc[11];
#pragma unroll
    for (int k = 0; k < 11; k++) acc[k] = make_float2(0.f, 0.f);
#pragma unroll
    for (int f = 0; f < F; f++) {
        float av = a[f];
        const float2* bp = reinterpret_cast<const float2*>(Bs + f * 88 + j0);
#pragma unroll
        for (int k = 0; k < 11; k++) {
            float2 b = bp[k];
            acc[k].x += av * b.x;
            acc[k].y += av * b.y;
        }
    }

    // stores: 2-col pairs never straddle region boundaries (40, 80, 84 all even)
#pragma unroll
    for (int k = 0; k < 11; k++) {
        int j = j0 + 2 * k;
        float2 v = acc[k];
        if (j < 40) {
            *reinterpret_cast<float2*>(xw + (size_t)r * 40 + j) = v;
        } else if (j < 80) {
            int jj = j - 40;
            v.x += bias[jj] + lbias[jj];
            v.y += bias[jj + 1] + lbias[jj + 1];
            *reinterpret_cast<float2*>(agg + (size_t)r * 40 + jj) = v;
        } else if (j < 84) {
            *reinterpret_cast<float2*>(asrc + (size_t)r * 8 + (j - 80)) = v;
        } else {
            *reinterpret_cast<float2*>(adst + (size_t)r * 8 + (j - 84)) = v;
        }
    }
}

// ---------------- layer 3 scores + bf16 h2 copy into A buffer ----------------
__global__ __launch_bounds__(256)
void feature3_kernel(const float* __restrict__ A, const float* __restrict__ B,
                     float* __restrict__ asrc, float* __restrict__ adst,
                     __hip_bfloat16* __restrict__ zb) {
    int r = blockIdx.x * 256 + threadIdx.x;
    if (r >= NN) return;
    float a[40];
    const float4* A4 = reinterpret_cast<const float4*>(A + (size_t)r * 40);
#pragma unroll
    for (int q = 0; q < 10; q++) {
        float4 v = A4[q];
        a[4 * q] = v.x; a[4 * q + 1] = v.y; a[4 * q + 2] = v.z; a[4 * q + 3] = v.w;
    }
    __hip_bfloat16* zr = zb + (size_t)r * 288 + 240;
#pragma unroll
    for (int f = 0; f < 40; f++) zr[f] = __float2bfloat16(a[f]);
#pragma unroll
    for (int f = 40; f < 48; f++) zr[f] = __float2bfloat16(0.f);

    float acc[12];
#pragma unroll
    for (int k = 0; k < 12; k++) acc[k] = 0.f;
#pragma unroll
    for (int f = 0; f < 40; f++) {
        float av = a[f];
#pragma unroll
        for (int k = 0; k < 12; k++) acc[k] += av * B[f * 12 + k];
    }
    *reinterpret_cast<float4*>(asrc + (size_t)r * 8) = make_float4(acc[0], acc[1], acc[2], acc[3]);
    *reinterpret_cast<float2*>(asrc + (size_t)r * 8 + 4) = make_float2(acc[4], acc[5]);
    *reinterpret_cast<float4*>(adst + (size_t)r * 8) = make_float4(acc[6], acc[7], acc[8], acc[9]);
    *reinterpret_cast<float2*>(adst + (size_t)r * 8 + 4) = make_float2(acc[10], acc[11]);
}

// ---------------- CSR aggregation, H=4 (layers 1/2), unroll x4 ----------------
__global__ __launch_bounds__(256)
void agg4_csr_kernel(const int* __restrict__ off, const int* __restrict__ srt,
                     const float* __restrict__ asrc, const float* __restrict__ adst,
                     const float* __restrict__ xw, float* agg) {
    int wid = ((blockIdx.x * 256 + threadIdx.x) >> 6);
    int d = __builtin_amdgcn_readfirstlane(wid);
    if (d >= NN) return;
    int lane = threadIdx.x & 63;
    bool act = lane < 40;
    int f = act ? lane : 0;
    int hh = f / 10;
    float adv = adst[(size_t)d * 8 + hh];
    int jb = off[d], je = off[d + 1];
    float acc = 0.f, ds = 0.f;
    int j = jb;
    for (; j + 3 < je; j += 4) {
        int s0 = srt[j], s1 = srt[j + 1], s2 = srt[j + 2], s3 = srt[j + 3];
        float e0 = asrc[(size_t)s0 * 8 + hh], e1 = asrc[(size_t)s1 * 8 + hh];
        float e2 = asrc[(size_t)s2 * 8 + hh], e3 = asrc[(size_t)s3 * 8 + hh];
        float x0 = xw[(size_t)s0 * 40 + f], x1 = xw[(size_t)s1 * 40 + f];
        float x2 = xw[(size_t)s2 * 40 + f], x3 = xw[(size_t)s3 * 40 + f];
        float w0 = __expf(lrelu(e0 + adv)), w1 = __expf(lrelu(e1 + adv));
        float w2 = __expf(lrelu(e2 + adv)), w3 = __expf(lrelu(e3 + adv));
        acc += w0 * x0; acc += w1 * x1; acc += w2 * x2; acc += w3 * x3;
        ds += (w0 + w1) + (w2 + w3);
    }
    for (; j < je; ++j) {
        int s = srt[j];
        float w = __expf(lrelu(asrc[(size_t)s * 8 + hh] + adv));
        acc += w * xw[(size_t)s * 40 + f];
        ds += w;
    }
    if (act) agg[(size_t)d * 40 + f] += acc / ds;
}

// ---------------- CSR aggregation, H=6 -> bf16 z, unroll x2 ----------------
__global__ __launch_bounds__(256)
void z6_csr_kernel(const int* __restrict__ off, const int* __restrict__ srt,
                   const float* __restrict__ asrc, const float* __restrict__ adst,
                   __hip_bfloat16* zb) {
    int wid = ((blockIdx.x * 256 + threadIdx.x) >> 6);
    int d = __builtin_amdgcn_readfirstlane(wid);
    if (d >= NN) return;
    int lane = threadIdx.x & 63;
    bool act = lane < 40;
    int f = act ? lane : 0;
    float adv[6];
#pragma unroll
    for (int h = 0; h < 6; h++) adv[h] = adst[(size_t)d * 8 + h];
    int jb = off[d], je = off[d + 1];
    float acc[6], ds[6];
#pragma unroll
    for (int h = 0; h < 6; h++) { acc[h] = 0.f; ds[h] = 0.f; }
    int j = jb;
    for (; j + 1 < je; j += 2) {
        int s0 = srt[j], s1 = srt[j + 1];
        float hv0 = __bfloat162float(zb[(size_t)s0 * 288 + 240 + f]);
        float hv1 = __bfloat162float(zb[(size_t)s1 * 288 + 240 + f]);
        float4 p0 = *reinterpret_cast<const float4*>(asrc + (size_t)s0 * 8);
        float2 q0 = *reinterpret_cast<const float2*>(asrc + (size_t)s0 * 8 + 4);
        float4 p1 = *reinterpret_cast<const float4*>(asrc + (size_t)s1 * 8);
        float2 q1 = *reinterpret_cast<const float2*>(asrc + (size_t)s1 * 8 + 4);
        float sv0[6] = {p0.x, p0.y, p0.z, p0.w, q0.x, q0.y};
        float sv1[6] = {p1.x, p1.y, p1.z, p1.w, q1.x, q1.y};
#pragma unroll
        for (int h = 0; h < 6; h++) {
            float w0 = __expf(lrelu(sv0[h] + adv[h]));
            float w1 = __expf(lrelu(sv1[h] + adv[h]));
            acc[h] += w0 * hv0; acc[h] += w1 * hv1;
            ds[h] += w0 + w1;
        }
    }
    for (; j < je; ++j) {
        int s = srt[j];
        float hv = __bfloat162float(zb[(size_t)s * 288 + 240 + f]);
        float4 p = *reinterpret_cast<const float4*>(asrc + (size_t)s * 8);
        float2 q = *reinterpret_cast<const float2*>(asrc + (size_t)s * 8 + 4);
        float sv[6] = {p.x, p.y, p.z, p.w, q.x, q.y};
#pragma unroll
        for (int h = 0; h < 6; h++) {
            float w = __expf(lrelu(sv[h] + adv[h]));
            acc[h] += w * hv;
            ds[h] += w;
        }
    }
    if (act) {
#pragma unroll
        for (int h = 0; h < 6; h++)
            zb[(size_t)d * 288 + h * 40 + f] =
                __float2bfloat16(acc[h] / ds[h] * (1.0f / 6.0f));
    }
}

// ---------------- ELU in-place ----------------
__global__ __launch_bounds__(256)
void elu_kernel(float4* p, int n4) {
    int t = blockIdx.x * 256 + threadIdx.x;
    if (t >= n4) return;
    float4 v = p[t];
    v.x = elu1(v.x); v.y = elu1(v.y); v.z = elu1(v.z); v.w = elu1(v.w);
    p[t] = v;
}

// ---------------- MFMA GEMM: out[100000x121] = A[100000x288]@B[288x128] + bias ----------------
__global__ __launch_bounds__(256)
void zgemm_mfma_kernel(const __hip_bfloat16* __restrict__ Ab,
                       const __hip_bfloat16* __restrict__ Bf,
                       const float* __restrict__ b3, const float* __restrict__ lb3,
                       float* __restrict__ out) {
    const int t = threadIdx.x;
    const int lane = t & 63, w = t >> 6;
    const int wr = w & 1, wc = w >> 1;
    const int n0 = blockIdx.x * 128;
    const short* As = (const short*)Ab;
    const short* Bs = (const short*)Bf;

    f32x4 acc[4][4];
#pragma unroll
    for (int i = 0; i < 4; i++)
#pragma unroll
        for (int j = 0; j < 4; j++) acc[i][j] = (f32x4){0.f, 0.f, 0.f, 0.f};

    const int arow = n0 + wr * 64 + (lane & 15);
    const int koff = (lane >> 4) * 8;

    for (int kk = 0; kk < 9; kk++) {
        bf16x8 af[4], bfr[4];
#pragma unroll
        for (int i = 0; i < 4; i++) {
            int r = arow + i * 16; if (r > NN - 1) r = NN - 1;
            af[i] = *(const bf16x8*)(As + (size_t)r * 288 + kk * 32 + koff);
        }
#pragma unroll
        for (int j = 0; j < 4; j++) {
            int ct = wc * 4 + j;
            bfr[j] = *(const bf16x8*)(Bs + (((size_t)kk * 8 + ct) * 64 + lane) * 8);
        }
#pragma unroll
        for (int i = 0; i < 4; i++)
#pragma unroll
            for (int j = 0; j < 4; j++)
                acc[i][j] = __builtin_amdgcn_mfma_f32_16x16x32_bf16(af[i], bfr[j], acc[i][j], 0, 0, 0);
    }

    const int c_base = wc * 64 + (lane & 15);
    const int r_quad = (lane >> 4) * 4;
#pragma unroll
    for (int j = 0; j < 4; j++) {
        int c = c_base + j * 16;
        if (c >= COUT) continue;
        float bias = b3[c] + lb3[c];
#pragma unroll
        for (int i = 0; i < 4; i++) {
            int nb = n0 + wr * 64 + i * 16 + r_quad;
#pragma unroll
            for (int q = 0; q < 4; q++) {
                int n = nb + q;
                if (n < NN) out[(size_t)n * COUT + c] = acc[i][j][q] + bias;
            }
        }
    }
}

extern "C" void kernel_launch(void* const* d_in, const int* in_sizes, int n_in,
                              void* d_out, int out_size, void* d_ws, size_t ws_size,
                              hipStream_t stream) {
    const float* x   = (const float*)d_in[0];
    const int*   ei  = (const int*)d_in[1];
    const float* W1  = (const float*)d_in[2];
    const float* as1 = (const float*)d_in[3];
    const float* ad1 = (const float*)d_in[4];
    const float* b1  = (const float*)d_in[5];
    const float* lw1 = (const float*)d_in[6];
    const float* lb1 = (const float*)d_in[7];
    const float* W2  = (const float*)d_in[8];
    const float* as2 = (const float*)d_in[9];
    const float* ad2 = (const float*)d_in[10];
    const float* b2  = (const float*)d_in[11];
    const float* lw2 = (const float*)d_in[12];
    const float* lb2 = (const float*)d_in[13];
    const float* W3  = (const float*)d_in[14];
    const float* as3 = (const float*)d_in[15];
    const float* ad3 = (const float*)d_in[16];
    const float* b3  = (const float*)d_in[17];
    const float* lw3 = (const float*)d_in[18];
    const float* lb3 = (const float*)d_in[19];
    float* out = (float*)d_out;
    float* ws  = (float*)d_ws;

    const int* esrc = ei;
    const int* edst = ei + NE;

    // ---- workspace layout ----
    float* xw   = ws;                               // 4,000,000
    float* agg  = ws + 4000000;                     // 4,000,000 (h after ELU)
    float* asrc = ws + 8000000;                     // 800,000
    float* adst = ws + 8800000;                     // 800,000
    float* Bc   = ws + 9600000;                     // 8,000
    __hip_bfloat16* Bf = (__hip_bfloat16*)(ws + 9608000);   // 36,864 bf16
    __hip_bfloat16* zb = (__hip_bfloat16*)(ws + 9628000);   // 100000*288 bf16
    int* ib     = (int*)(ws + 24028000);
    int* deg    = ib;
    int* off    = ib + 100352;
    int* cursor = ib + 200704;
    int* bsum   = ib + 300704;
    int* bscan  = ib + 301216;
    int* sorted = ib + 301728;

    const int nodeBlocks = (NN + 255) / 256;       // 391
    const int edgeBlocks = (NE + 255) / 256;       // 6250
    const int waveBlocks = NN / 4;                 // 25000
    const int featBlocks = (NN * 4 + 255) / 256;   // 1563

    // ---- CSR build ----
    deg_init_kernel<<<nodeBlocks, 256, 0, stream>>>(deg);
    hist_kernel<<<edgeBlocks, 256, 0, stream>>>(edst, deg);
    scan_block_kernel<<<nodeBlocks, 256, 0, stream>>>(deg, off, bsum);
    scan_bsum_kernel<<<1, 256, 0, stream>>>(bsum, bscan, nodeBlocks);
    place_kernel<<<nodeBlocks, 256, 0, stream>>>(off, bscan, sorted, cursor);
    scatter_kernel<<<edgeBlocks, 256, 0, stream>>>(esrc, edst, cursor, sorted);

    // ---- layer 1 ----
    fold_B12_kernel<<<(FIN * 88 + 255) / 256, 256, 0, stream>>>(W1, lw1, as1, ad1, Bc, FIN);
    feature12_kernel<FIN><<<featBlocks, 256, 0, stream>>>(x, Bc, b1, lb1, xw, agg, asrc, adst);
    agg4_csr_kernel<<<waveBlocks, 256, 0, stream>>>(off, sorted, asrc, adst, xw, agg);
    elu_kernel<<<(NN * 40 / 4 + 255) / 256, 256, 0, stream>>>((float4*)agg, NN * 40 / 4);

    // ---- layer 2 ----
    fold_B12_kernel<<<(HID * 88 + 255) / 256, 256, 0, stream>>>(W2, lw2, as2, ad2, Bc, HID);
    feature12_kernel<HID><<<featBlocks, 256, 0, stream>>>(agg, Bc, b2, lb2, xw, agg, asrc, adst);
    agg4_csr_kernel<<<waveBlocks, 256, 0, stream>>>(off, sorted, asrc, adst, xw, agg);
    elu_kernel<<<(NN * 40 / 4 + 255) / 256, 256, 0, stream>>>((float4*)agg, NN * 40 / 4);

    // ---- layer 3 ----
    fold_B3_kernel<<<(40 * 12 + 255) / 256, 256, 0, stream>>>(W3, as3, ad3, Bc);
    fold_Bf_kernel<<<(9 * 8 * 64 * 8 + 255) / 256, 256, 0, stream>>>(W3, lw3, Bf);
    feature3_kernel<<<nodeBlocks, 256, 0, stream>>>(agg, Bc, asrc, adst, zb);
    z6_csr_kernel<<<waveBlocks, 256, 0, stream>>>(off, sorted, asrc, adst, zb);
    zgemm_mfma_kernel<<<(NN + 127) / 128, 256, 0, stream>>>(zb, Bf, b3, lb3, out);
}

// Round 5
// 809.828 us; speedup vs baseline: 2.1539x; 2.1539x over previous
//
#include <hip/hip_runtime.h>
#include <hip/hip_bf16.h>
#include <math.h>

// GAT x3 on N=100000 nodes, E=1600000 edges (+ self loops).
// Round 5: feature12 = round-3 register structure (a[F] in VGPRs, acc[8] per
// column-group, B via L1) but 4 threads/row taking strided column-groups
// (g = p, p+4, ...). 400k threads -> 24 waves/CU without spills.
// ELU fused into agg4 epilogue (elu_kernel launches removed).

#define NN 100000
#define NE 1600000
#define NT (NE + NN)
#define FIN 50
#define HID 40
#define COUT 121

typedef __attribute__((ext_vector_type(8))) short bf16x8;
typedef __attribute__((ext_vector_type(4))) float f32x4;

__device__ __forceinline__ float lrelu(float x) { return fmaxf(x, 0.2f * x); }
__device__ __forceinline__ float elu1(float x)  { return x > 0.f ? x : __expf(x) - 1.f; }

// ---------------- CSR build ----------------
__global__ __launch_bounds__(256)
void deg_init_kernel(int* __restrict__ deg) {
    int i = blockIdx.x * 256 + threadIdx.x;
    if (i < NN) deg[i] = 1;  // self loop
}

__global__ __launch_bounds__(256)
void hist_kernel(const int* __restrict__ edst, int* __restrict__ deg) {
    int e = blockIdx.x * 256 + threadIdx.x;
    if (e < NE) atomicAdd(&deg[edst[e]], 1);
}

__global__ __launch_bounds__(256)
void scan_block_kernel(const int* __restrict__ deg, int* __restrict__ off,
                       int* __restrict__ bsum) {
    __shared__ int s[256];
    int t = threadIdx.x, b = blockIdx.x, i = b * 256 + t;
    int v = (i < NN) ? deg[i] : 0;
    s[t] = v; __syncthreads();
#pragma unroll
    for (int o = 1; o < 256; o <<= 1) {
        int x = (t >= o) ? s[t - o] : 0;
        __syncthreads();
        s[t] += x;
        __syncthreads();
    }
    if (i < NN) off[i] = s[t] - v;
    if (t == 255) bsum[b] = s[255];
}

__global__ __launch_bounds__(256)
void scan_bsum_kernel(const int* __restrict__ bsum, int* __restrict__ bscan, int nb) {
    __shared__ int s[256];
    int t = threadIdx.x;
    int carry = 0;
    int nc = (nb + 255) / 256;
    for (int c = 0; c < nc; c++) {
        int i = c * 256 + t;
        int v = (i < nb) ? bsum[i] : 0;
        s[t] = v; __syncthreads();
#pragma unroll
        for (int o = 1; o < 256; o <<= 1) {
            int x = (t >= o) ? s[t - o] : 0;
            __syncthreads();
            s[t] += x;
            __syncthreads();
        }
        if (i < nb) bscan[i] = carry + s[t] - v;
        carry += s[255];
        __syncthreads();
    }
}

__global__ __launch_bounds__(256)
void place_kernel(int* __restrict__ off, const int* __restrict__ bscan,
                  int* __restrict__ sorted_src, int* __restrict__ cursor) {
    int i = blockIdx.x * 256 + threadIdx.x;
    if (i == 0) off[NN] = NT;
    if (i < NN) {
        int o = off[i] + bscan[i >> 8];
        off[i] = o;
        sorted_src[o] = i;   // self loop first
        cursor[i] = o + 1;
    }
}

__global__ __launch_bounds__(256)
void scatter_kernel(const int* __restrict__ esrc, const int* __restrict__ edst,
                    int* __restrict__ cursor, int* __restrict__ sorted_src) {
    int e = blockIdx.x * 256 + threadIdx.x;
    if (e < NE) {
        int d = edst[e];
        int p = atomicAdd(&cursor[d], 1);
        sorted_src[p] = esrc[e];
    }
}

// ---------------- fold weight blocks ----------------
__global__ __launch_bounds__(256)
void fold_B12_kernel(const float* __restrict__ W, const float* __restrict__ lw,
                     const float* __restrict__ as_, const float* __restrict__ ad_,
                     float* __restrict__ B, int F) {
    int t = blockIdx.x * 256 + threadIdx.x;
    if (t >= F * 88) return;
    int f = t / 88, j = t - f * 88;
    float v = 0.f;
    if (j < 40) v = W[f * 40 + j];
    else if (j < 80) v = lw[f * 40 + (j - 40)];
    else if (j < 84) {
        int h = j - 80; float s = 0.f;
        for (int d = 0; d < 10; d++) s += W[f * 40 + h * 10 + d] * as_[h * 10 + d];
        v = s;
    } else {
        int h = j - 84; float s = 0.f;
        for (int d = 0; d < 10; d++) s += W[f * 40 + h * 10 + d] * ad_[h * 10 + d];
        v = s;
    }
    B[t] = v;
}

__global__ __launch_bounds__(256)
void fold_B3_kernel(const float* __restrict__ W3, const float* __restrict__ as3,
                    const float* __restrict__ ad3, float* __restrict__ B) {
    int t = blockIdx.x * 256 + threadIdx.x;
    if (t >= 40 * 12) return;
    int f = t / 12, k = t - f * 12;
    float s = 0.f;
    if (k < 6) {
        int h = k;
        for (int c = 0; c < COUT; c++) s += W3[f * 726 + h * COUT + c] * as3[h * COUT + c];
    } else {
        int h = k - 6;
        for (int c = 0; c < COUT; c++) s += W3[f * 726 + h * COUT + c] * ad3[h * COUT + c];
    }
    B[t] = s;
}

// Fold W3/lw3 into bf16 MFMA B-fragment order (see round-3 comment).
__global__ __launch_bounds__(256)
void fold_Bf_kernel(const float* __restrict__ W3, const float* __restrict__ lw3,
                    __hip_bfloat16* __restrict__ Bf) {
    int t = blockIdx.x * 256 + threadIdx.x;
    if (t >= 9 * 8 * 64 * 8) return;
    int j = t & 7, lane = (t >> 3) & 63, ct = (t >> 9) & 7, kt = t >> 12;
    int k = kt * 32 + (lane >> 4) * 8 + j;
    int c = ct * 16 + (lane & 15);
    float v = 0.f;
    if (c < COUT) {
        if (k < 240) {
            int h = k / 40, f = k - h * 40;
            v = W3[f * 726 + h * COUT + c];
        } else if (k < 280) {
            int f = k - 240;
            v = lw3[f * COUT + c];
        }
    }
    Bf[t] = __float2bfloat16(v);
}

// ---------------- fused feature GEMM for layers 1/2 ----------------
// 4 threads per row; thread p handles column-groups g = p, p+4, ... (of 11
// groups of 8 cols). Round-3 register economy: a[F] + acc[8] live only.
template <int F>
__global__ __launch_bounds__(256)
void feature12_kernel(const float* A, const float* __restrict__ B,
                      const float* __restrict__ bias, const float* __restrict__ lbias,
                      float* __restrict__ xw, float* agg,
                      float* __restrict__ asrc, float* __restrict__ adst) {
    int g0 = blockIdx.x * 256 + threadIdx.x;
    int r = g0 >> 2, p = g0 & 3;
    if (r >= NN) return;

    float a[F];
    if (F % 4 == 0) {
        const float4* A4 = reinterpret_cast<const float4*>(A + (size_t)r * F);
#pragma unroll
        for (int q = 0; q < F / 4; q++) {
            float4 v = A4[q];
            a[4 * q] = v.x; a[4 * q + 1] = v.y; a[4 * q + 2] = v.z; a[4 * q + 3] = v.w;
        }
    } else {
        const float2* A2 = reinterpret_cast<const float2*>(A + (size_t)r * F);
#pragma unroll
        for (int q = 0; q < F / 2; q++) {
            float2 v = A2[q];
            a[2 * q] = v.x; a[2 * q + 1] = v.y;
        }
        if (F & 1) a[F - 1] = A[(size_t)r * F + F - 1];
    }

    for (int g = p; g < 11; g += 4) {
        const int j0 = g * 8;
        float acc[8];
#pragma unroll
        for (int k = 0; k < 8; k++) acc[k] = 0.f;
#pragma unroll
        for (int f = 0; f < F; f++) {
            float av = a[f];
#pragma unroll
            for (int k = 0; k < 8; k++) acc[k] += av * B[f * 88 + j0 + k];
        }
        if (j0 < 40) {
            *reinterpret_cast<float4*>(xw + (size_t)r * 40 + j0) =
                make_float4(acc[0], acc[1], acc[2], acc[3]);
            *reinterpret_cast<float4*>(xw + (size_t)r * 40 + j0 + 4) =
                make_float4(acc[4], acc[5], acc[6], acc[7]);
        } else if (j0 < 80) {
            int j = j0 - 40;
#pragma unroll
            for (int k = 0; k < 8; k++) acc[k] += bias[j + k] + lbias[j + k];
            *reinterpret_cast<float4*>(agg + (size_t)r * 40 + j) =
                make_float4(acc[0], acc[1], acc[2], acc[3]);
            *reinterpret_cast<float4*>(agg + (size_t)r * 40 + j + 4) =
                make_float4(acc[4], acc[5], acc[6], acc[7]);
        } else {
            *reinterpret_cast<float4*>(asrc + (size_t)r * 8) =
                make_float4(acc[0], acc[1], acc[2], acc[3]);
            *reinterpret_cast<float4*>(adst + (size_t)r * 8) =
                make_float4(acc[4], acc[5], acc[6], acc[7]);
        }
    }
}

// ---------------- layer 3 scores + bf16 h2 copy into A buffer ----------------
__global__ __launch_bounds__(256)
void feature3_kernel(const float* __restrict__ A, const float* __restrict__ B,
                     float* __restrict__ asrc, float* __restrict__ adst,
                     __hip_bfloat16* __restrict__ zb) {
    int r = blockIdx.x * 256 + threadIdx.x;
    if (r >= NN) return;
    float a[40];
    const float4* A4 = reinterpret_cast<const float4*>(A + (size_t)r * 40);
#pragma unroll
    for (int q = 0; q < 10; q++) {
        float4 v = A4[q];
        a[4 * q] = v.x; a[4 * q + 1] = v.y; a[4 * q + 2] = v.z; a[4 * q + 3] = v.w;
    }
    __hip_bfloat16* zr = zb + (size_t)r * 288 + 240;
#pragma unroll
    for (int f = 0; f < 40; f++) zr[f] = __float2bfloat16(a[f]);
#pragma unroll
    for (int f = 40; f < 48; f++) zr[f] = __float2bfloat16(0.f);

    float acc[12];
#pragma unroll
    for (int k = 0; k < 12; k++) acc[k] = 0.f;
#pragma unroll
    for (int f = 0; f < 40; f++) {
        float av = a[f];
#pragma unroll
        for (int k = 0; k < 12; k++) acc[k] += av * B[f * 12 + k];
    }
    *reinterpret_cast<float4*>(asrc + (size_t)r * 8) = make_float4(acc[0], acc[1], acc[2], acc[3]);
    *reinterpret_cast<float2*>(asrc + (size_t)r * 8 + 4) = make_float2(acc[4], acc[5]);
    *reinterpret_cast<float4*>(adst + (size_t)r * 8) = make_float4(acc[6], acc[7], acc[8], acc[9]);
    *reinterpret_cast<float2*>(adst + (size_t)r * 8 + 4) = make_float2(acc[10], acc[11]);
}

// ---------------- CSR aggregation, H=4 (layers 1/2), unroll x4, fused ELU ----
__global__ __launch_bounds__(256)
void agg4_csr_kernel(const int* __restrict__ off, const int* __restrict__ srt,
                     const float* __restrict__ asrc, const float* __restrict__ adst,
                     const float* __restrict__ xw, float* agg) {
    int wid = ((blockIdx.x * 256 + threadIdx.x) >> 6);
    int d = __builtin_amdgcn_readfirstlane(wid);
    if (d >= NN) return;
    int lane = threadIdx.x & 63;
    bool act = lane < 40;
    int f = act ? lane : 0;
    int hh = f / 10;
    float adv = adst[(size_t)d * 8 + hh];
    int jb = off[d], je = off[d + 1];
    float acc = 0.f, ds = 0.f;
    int j = jb;
    for (; j + 3 < je; j += 4) {
        int s0 = srt[j], s1 = srt[j + 1], s2 = srt[j + 2], s3 = srt[j + 3];
        float e0 = asrc[(size_t)s0 * 8 + hh], e1 = asrc[(size_t)s1 * 8 + hh];
        float e2 = asrc[(size_t)s2 * 8 + hh], e3 = asrc[(size_t)s3 * 8 + hh];
        float x0 = xw[(size_t)s0 * 40 + f], x1 = xw[(size_t)s1 * 40 + f];
        float x2 = xw[(size_t)s2 * 40 + f], x3 = xw[(size_t)s3 * 40 + f];
        float w0 = __expf(lrelu(e0 + adv)), w1 = __expf(lrelu(e1 + adv));
        float w2 = __expf(lrelu(e2 + adv)), w3 = __expf(lrelu(e3 + adv));
        acc += w0 * x0; acc += w1 * x1; acc += w2 * x2; acc += w3 * x3;
        ds += (w0 + w1) + (w2 + w3);
    }
    for (; j < je; ++j) {
        int s = srt[j];
        float w = __expf(lrelu(asrc[(size_t)s * 8 + hh] + adv));
        acc += w * xw[(size_t)s * 40 + f];
        ds += w;
    }
    if (act) {
        float v = agg[(size_t)d * 40 + f] + acc / ds;
        agg[(size_t)d * 40 + f] = elu1(v);   // ELU fused (layers 1/2 only)
    }
}

// ---------------- CSR aggregation, H=6 -> bf16 z, unroll x2 ----------------
__global__ __launch_bounds__(256)
void z6_csr_kernel(const int* __restrict__ off, const int* __restrict__ srt,
                   const float* __restrict__ asrc, const float* __restrict__ adst,
                   __hip_bfloat16* zb) {
    int wid = ((blockIdx.x * 256 + threadIdx.x) >> 6);
    int d = __builtin_amdgcn_readfirstlane(wid);
    if (d >= NN) return;
    int lane = threadIdx.x & 63;
    bool act = lane < 40;
    int f = act ? lane : 0;
    float adv[6];
#pragma unroll
    for (int h = 0; h < 6; h++) adv[h] = adst[(size_t)d * 8 + h];
    int jb = off[d], je = off[d + 1];
    float acc[6], ds[6];
#pragma unroll
    for (int h = 0; h < 6; h++) { acc[h] = 0.f; ds[h] = 0.f; }
    int j = jb;
    for (; j + 1 < je; j += 2) {
        int s0 = srt[j], s1 = srt[j + 1];
        float hv0 = __bfloat162float(zb[(size_t)s0 * 288 + 240 + f]);
        float hv1 = __bfloat162float(zb[(size_t)s1 * 288 + 240 + f]);
        float4 p0 = *reinterpret_cast<const float4*>(asrc + (size_t)s0 * 8);
        float2 q0 = *reinterpret_cast<const float2*>(asrc + (size_t)s0 * 8 + 4);
        float4 p1 = *reinterpret_cast<const float4*>(asrc + (size_t)s1 * 8);
        float2 q1 = *reinterpret_cast<const float2*>(asrc + (size_t)s1 * 8 + 4);
        float sv0[6] = {p0.x, p0.y, p0.z, p0.w, q0.x, q0.y};
        float sv1[6] = {p1.x, p1.y, p1.z, p1.w, q1.x, q1.y};
#pragma unroll
        for (int h = 0; h < 6; h++) {
            float w0 = __expf(lrelu(sv0[h] + adv[h]));
            float w1 = __expf(lrelu(sv1[h] + adv[h]));
            acc[h] += w0 * hv0; acc[h] += w1 * hv1;
            ds[h] += w0 + w1;
        }
    }
    for (; j < je; ++j) {
        int s = srt[j];
        float hv = __bfloat162float(zb[(size_t)s * 288 + 240 + f]);
        float4 p = *reinterpret_cast<const float4*>(asrc + (size_t)s * 8);
        float2 q = *reinterpret_cast<const float2*>(asrc + (size_t)s * 8 + 4);
        float sv[6] = {p.x, p.y, p.z, p.w, q.x, q.y};
#pragma unroll
        for (int h = 0; h < 6; h++) {
            float w = __expf(lrelu(sv[h] + adv[h]));
            acc[h] += w * hv;
            ds[h] += w;
        }
    }
    if (act) {
#pragma unroll
        for (int h = 0; h < 6; h++)
            zb[(size_t)d * 288 + h * 40 + f] =
                __float2bfloat16(acc[h] / ds[h] * (1.0f / 6.0f));
    }
}

// ---------------- MFMA GEMM: out[100000x121] = A[100000x288]@B[288x128] + bias ----------------
__global__ __launch_bounds__(256)
void zgemm_mfma_kernel(const __hip_bfloat16* __restrict__ Ab,
                       const __hip_bfloat16* __restrict__ Bf,
                       const float* __restrict__ b3, const float* __restrict__ lb3,
                       float* __restrict__ out) {
    const int t = threadIdx.x;
    const int lane = t & 63, w = t >> 6;
    const int wr = w & 1, wc = w >> 1;
    const int n0 = blockIdx.x * 128;
    const short* As = (const short*)Ab;
    const short* Bs = (const short*)Bf;

    f32x4 acc[4][4];
#pragma unroll
    for (int i = 0; i < 4; i++)
#pragma unroll
        for (int j = 0; j < 4; j++) acc[i][j] = (f32x4){0.f, 0.f, 0.f, 0.f};

    const int arow = n0 + wr * 64 + (lane & 15);
    const int koff = (lane >> 4) * 8;

    for (int kk = 0; kk < 9; kk++) {
        bf16x8 af[4], bfr[4];
#pragma unroll
        for (int i = 0; i < 4; i++) {
            int r = arow + i * 16; if (r > NN - 1) r = NN - 1;
            af[i] = *(const bf16x8*)(As + (size_t)r * 288 + kk * 32 + koff);
        }
#pragma unroll
        for (int j = 0; j < 4; j++) {
            int ct = wc * 4 + j;
            bfr[j] = *(const bf16x8*)(Bs + (((size_t)kk * 8 + ct) * 64 + lane) * 8);
        }
#pragma unroll
        for (int i = 0; i < 4; i++)
#pragma unroll
            for (int j = 0; j < 4; j++)
                acc[i][j] = __builtin_amdgcn_mfma_f32_16x16x32_bf16(af[i], bfr[j], acc[i][j], 0, 0, 0);
    }

    const int c_base = wc * 64 + (lane & 15);
    const int r_quad = (lane >> 4) * 4;
#pragma unroll
    for (int j = 0; j < 4; j++) {
        int c = c_base + j * 16;
        if (c >= COUT) continue;
        float bias = b3[c] + lb3[c];
#pragma unroll
        for (int i = 0; i < 4; i++) {
            int nb = n0 + wr * 64 + i * 16 + r_quad;
#pragma unroll
            for (int q = 0; q < 4; q++) {
                int n = nb + q;
                if (n < NN) out[(size_t)n * COUT + c] = acc[i][j][q] + bias;
            }
        }
    }
}

extern "C" void kernel_launch(void* const* d_in, const int* in_sizes, int n_in,
                              void* d_out, int out_size, void* d_ws, size_t ws_size,
                              hipStream_t stream) {
    const float* x   = (const float*)d_in[0];
    const int*   ei  = (const int*)d_in[1];
    const float* W1  = (const float*)d_in[2];
    const float* as1 = (const float*)d_in[3];
    const float* ad1 = (const float*)d_in[4];
    const float* b1  = (const float*)d_in[5];
    const float* lw1 = (const float*)d_in[6];
    const float* lb1 = (const float*)d_in[7];
    const float* W2  = (const float*)d_in[8];
    const float* as2 = (const float*)d_in[9];
    const float* ad2 = (const float*)d_in[10];
    const float* b2  = (const float*)d_in[11];
    const float* lw2 = (const float*)d_in[12];
    const float* lb2 = (const float*)d_in[13];
    const float* W3  = (const float*)d_in[14];
    const float* as3 = (const float*)d_in[15];
    const float* ad3 = (const float*)d_in[16];
    const float* b3  = (const float*)d_in[17];
    const float* lw3 = (const float*)d_in[18];
    const float* lb3 = (const float*)d_in[19];
    float* out = (float*)d_out;
    float* ws  = (float*)d_ws;

    const int* esrc = ei;
    const int* edst = ei + NE;

    // ---- workspace layout ----
    float* xw   = ws;                               // 4,000,000
    float* agg  = ws + 4000000;                     // 4,000,000 (h after ELU)
    float* asrc = ws + 8000000;                     // 800,000
    float* adst = ws + 8800000;                     // 800,000
    float* Bc   = ws + 9600000;                     // 8,000
    __hip_bfloat16* Bf = (__hip_bfloat16*)(ws + 9608000);   // 36,864 bf16
    __hip_bfloat16* zb = (__hip_bfloat16*)(ws + 9628000);   // 100000*288 bf16
    int* ib     = (int*)(ws + 24028000);
    int* deg    = ib;
    int* off    = ib + 100352;
    int* cursor = ib + 200704;
    int* bsum   = ib + 300704;
    int* bscan  = ib + 301216;
    int* sorted = ib + 301728;

    const int nodeBlocks = (NN + 255) / 256;       // 391
    const int edgeBlocks = (NE + 255) / 256;       // 6250
    const int waveBlocks = NN / 4;                 // 25000
    const int featBlocks = (NN * 4 + 255) / 256;   // 1563

    // ---- CSR build ----
    deg_init_kernel<<<nodeBlocks, 256, 0, stream>>>(deg);
    hist_kernel<<<edgeBlocks, 256, 0, stream>>>(edst, deg);
    scan_block_kernel<<<nodeBlocks, 256, 0, stream>>>(deg, off, bsum);
    scan_bsum_kernel<<<1, 256, 0, stream>>>(bsum, bscan, nodeBlocks);
    place_kernel<<<nodeBlocks, 256, 0, stream>>>(off, bscan, sorted, cursor);
    scatter_kernel<<<edgeBlocks, 256, 0, stream>>>(esrc, edst, cursor, sorted);

    // ---- layer 1 ----
    fold_B12_kernel<<<(FIN * 88 + 255) / 256, 256, 0, stream>>>(W1, lw1, as1, ad1, Bc, FIN);
    feature12_kernel<FIN><<<featBlocks, 256, 0, stream>>>(x, Bc, b1, lb1, xw, agg, asrc, adst);
    agg4_csr_kernel<<<waveBlocks, 256, 0, stream>>>(off, sorted, asrc, adst, xw, agg);

    // ---- layer 2 ----
    fold_B12_kernel<<<(HID * 88 + 255) / 256, 256, 0, stream>>>(W2, lw2, as2, ad2, Bc, HID);
    feature12_kernel<HID><<<featBlocks, 256, 0, stream>>>(agg, Bc, b2, lb2, xw, agg, asrc, adst);
    agg4_csr_kernel<<<waveBlocks, 256, 0, stream>>>(off, sorted, asrc, adst, xw, agg);

    // ---- layer 3 ----
    fold_B3_kernel<<<(40 * 12 + 255) / 256, 256, 0, stream>>>(W3, as3, ad3, Bc);
    fold_Bf_kernel<<<(9 * 8 * 64 * 8 + 255) / 256, 256, 0, stream>>>(W3, lw3, Bf);
    feature3_kernel<<<nodeBlocks, 256, 0, stream>>>(agg, Bc, asrc, adst, zb);
    z6_csr_kernel<<<waveBlocks, 256, 0, stream>>>(off, sorted, asrc, adst, zb);
    zgemm_mfma_kernel<<<(NN + 127) / 128, 256, 0, stream>>>(zb, Bf, b3, lb3, out);
}